// Round 1
// baseline (242.029 us; speedup 1.0000x reference)
//
#include <hip/hip_runtime.h>
#include <hip/hip_bf16.h>

// Problem: B=4, N=2048, IN=256, H=8, ATN=32
//   xt = x@W + b; xC = xt@C^T; S = xC@xt^T; alpha = tanh(S*adj);
//   out = concat_h(alpha @ xt)  [B,N,256] fp32
//
// R9: counters said k_attn is stall-bound, not pipe-bound (MfmaUtil 8.8,
// VALUBusy 59 (gfx94x formula, ~2x inflated), HBM 15%, 2.1M LDS conflict
// cycles). The DMA->LDS->barrier choreography only buys INTRA-block sharing
// of a 4KB adj tile that has zero cross-block reuse -- L1 (32KB/CU) gives
// that sharing for free. So: drop LDS/DMA/barriers/fences entirely; each
// wave loads its own adj fragments as f32x4 straight from global, joined
// to the proven even/odd depth-1 register pipeline. Lane mapping derived
// from the R5 swizzle algebra: A00[j]=adj[n0+c][m0+8q+j], A01 next 16B,
// A10/A11 at row n0+16+c. All hazards are now plain data deps (no manual
// vmcnt arithmetic -> the R6/R7/R8 race class is structurally impossible).
// Numerics bit-identical to R8 (same values, same tanh, same MFMA order).
// Cost: ~+50 VGPR of prefetch (56 -> ~120, capped by launch_bounds(512,4)
// = 2 blocks/CU); acceptable since waves are now fully independent.

typedef __bf16 bf16;
typedef __attribute__((ext_vector_type(8))) __bf16 bf16x8;
typedef __attribute__((ext_vector_type(4))) __bf16 bf16x4;
typedef __attribute__((ext_vector_type(4))) float  f32x4;

#define MFMA(a, b, c) __builtin_amdgcn_mfma_f32_16x16x32_bf16(a, b, c, 0, 0, 0)

// Padé tanh (R5-proven scalar form): x(945+105t+t^2)/(945+420t+15t^2), clamped.
__device__ __forceinline__ float fast_tanh(float x) {
    float t   = x * x;
    float num = x * __builtin_fmaf(t, t + 105.0f, 945.0f);
    float den = __builtin_fmaf(t, __builtin_fmaf(t, 15.0f, 420.0f), 945.0f);
    float r   = num * __builtin_amdgcn_rcpf(den);
    return __builtin_amdgcn_fmed3f(r, -1.0f, 1.0f);
}

#define BB   4
#define NN   2048
#define IND  256
#define HH   8
#define ATN  32

// workspace layout (bytes) — total 25.3 MB (same proven footprint as R5)
#define OFF_XBF   0u           // x bf16 (4 MB); DEAD after k_proj -> reused as slab0
#define OFF_XT    4194304u
#define OFF_XC    8388608u
#define OFF_XTT   12582912u
#define OFF_WT    16777216u
#define OFF_CB    16908288u
#define OFF_SLAB  16924672u    // slab1 (4 MB bf16) + slab2 (4 MB bf16)

// ---------------- kernel 0: dtype conversion ----------------
__global__ __launch_bounds__(256) void k_prep(const float* __restrict__ x,
                                              const float* __restrict__ W,
                                              const float* __restrict__ C,
                                              bf16* __restrict__ xbf,
                                              bf16* __restrict__ WT,
                                              bf16* __restrict__ Cb) {
    int tid = blockIdx.x * 256 + threadIdx.x;
    if (tid < 524288) {
        float4 v = ((const float4*)x)[tid];
        bf16x4 o;
        o[0] = (bf16)v.x; o[1] = (bf16)v.y; o[2] = (bf16)v.z; o[3] = (bf16)v.w;
        *(bf16x4*)(xbf + (size_t)tid * 4) = o;
    } else if (tid < 524288 + 65536) {
        int t = tid - 524288;
        int h = t >> 13, r = t & 8191, i = r >> 5, o = r & 31;
        WT[(h * 32 + o) * 256 + i] = (bf16)W[t];
    } else if (tid < 524288 + 65536 + 8192) {
        int t = tid - (524288 + 65536);
        Cb[t] = (bf16)C[t];
    }
}

// ---------------- kernel A: projection ----------------
__global__ __launch_bounds__(256) void k_proj(const bf16* __restrict__ xbf,
                                              const bf16* __restrict__ WT,
                                              const bf16* __restrict__ Cb,
                                              const float* __restrict__ bias,
                                              bf16* __restrict__ xt,
                                              bf16* __restrict__ xc,
                                              bf16* __restrict__ xtT) {
    __shared__ bf16 ldsA_all[4][32 * 40];
    __shared__ bf16 ldsB_all[4][32 * 40];
    int bid = blockIdx.x;
    int ntg = bid & 15, h = (bid >> 4) & 7, b = bid >> 7;
    int wave = threadIdx.x >> 6;
    int lane = threadIdx.x & 63;
    int nt = ntg * 4 + wave;
    int n0 = nt * 32;
    int c = lane & 15, q = lane >> 4;
    bf16* ldsA = ldsA_all[wave];
    bf16* ldsB = ldsB_all[wave];

    f32x4 acc[2][2] = {};
    const bf16* xrow0 = xbf + ((size_t)(b * NN + n0 + c) * IND + q * 8);
    const bf16* xrow1 = xbf + ((size_t)(b * NN + n0 + 16 + c) * IND + q * 8);
    const bf16* wrow0 = WT + ((h * 32 + c) * IND + q * 8);
    const bf16* wrow1 = WT + ((h * 32 + 16 + c) * IND + q * 8);
#pragma unroll
    for (int k0 = 0; k0 < IND; k0 += 32) {
        bf16x8 a0 = *(const bf16x8*)(xrow0 + k0);
        bf16x8 a1 = *(const bf16x8*)(xrow1 + k0);
        bf16x8 w0 = *(const bf16x8*)(wrow0 + k0);
        bf16x8 w1 = *(const bf16x8*)(wrow1 + k0);
        acc[0][0] = MFMA(a0, w0, acc[0][0]);
        acc[0][1] = MFMA(a0, w1, acc[0][1]);
        acc[1][0] = MFMA(a1, w0, acc[1][0]);
        acc[1][1] = MFMA(a1, w1, acc[1][1]);
    }
    float bv[2] = { bias[h * 32 + c], bias[h * 32 + 16 + c] };
    size_t bh = (size_t)(b * HH + h);
#pragma unroll
    for (int nq = 0; nq < 2; ++nq)
#pragma unroll
        for (int oq = 0; oq < 2; ++oq)
#pragma unroll
            for (int r = 0; r < 4; ++r)
                ldsA[(nq * 16 + q * 4 + r) * 40 + oq * 16 + c] =
                    (bf16)(acc[nq][oq][r] + bv[oq]);
    f32x4 acc2[2][2] = {};
    bf16x8 aL0 = *(const bf16x8*)(ldsA + (c) * 40 + q * 8);
    bf16x8 aL1 = *(const bf16x8*)(ldsA + (16 + c) * 40 + q * 8);
    bf16x8 c0 = *(const bf16x8*)(Cb + h * 1024 + (c) * 32 + q * 8);
    bf16x8 c1 = *(const bf16x8*)(Cb + h * 1024 + (16 + c) * 32 + q * 8);
    acc2[0][0] = MFMA(aL0, c0, acc2[0][0]);
    acc2[0][1] = MFMA(aL0, c1, acc2[0][1]);
    acc2[1][0] = MFMA(aL1, c0, acc2[1][0]);
    acc2[1][1] = MFMA(aL1, c1, acc2[1][1]);
#pragma unroll
    for (int nq = 0; nq < 2; ++nq)
#pragma unroll
        for (int pq = 0; pq < 2; ++pq)
#pragma unroll
            for (int r = 0; r < 4; ++r)
                ldsB[(nq * 16 + q * 4 + r) * 40 + pq * 16 + c] =
                    (bf16)acc2[nq][pq][r];

    {   // coalesced xt/xc stores
        int n = lane >> 1, half = lane & 1;
        bf16x8 t0 = *(const bf16x8*)(ldsA + n * 40 + half * 16);
        bf16x8 t1 = *(const bf16x8*)(ldsA + n * 40 + half * 16 + 8);
        bf16* dst = xt + (bh * NN + n0 + n) * ATN + half * 16;
        *(bf16x8*)(dst) = t0;
        *(bf16x8*)(dst + 8) = t1;
        bf16x8 u0 = *(const bf16x8*)(ldsB + n * 40 + half * 16);
        bf16x8 u1 = *(const bf16x8*)(ldsB + n * 40 + half * 16 + 8);
        bf16* dst2 = xc + (bh * NN + n0 + n) * ATN + half * 16;
        *(bf16x8*)(dst2) = u0;
        *(bf16x8*)(dst2 + 8) = u1;
    }
    {   // xtT via LDS-gathered transpose
        int o = lane >> 1, nh = lane & 1;
        bf16x8 t0, t1;
#pragma unroll
        for (int i = 0; i < 8; ++i) {
            t0[i] = ldsA[(nh * 16 + i) * 40 + o];
            t1[i] = ldsA[(nh * 16 + 8 + i) * 40 + o];
        }
        bf16* dst = xtT + (bh * ATN + o) * NN + n0 + nh * 16;
        *(bf16x8*)(dst) = t0;
        *(bf16x8*)(dst + 8) = t1;
    }
}

// ---------------- kernel B: fused scores/tanh/PV, barrier-free ----------------
// grid 1024 = chunk(4) * b(4) * ntile(64); 512 thr = 8 waves; wave == head.
// No LDS, no barriers: each wave streams its own adj fragments (f32x4
// global loads, 32 full 128B lines per 32x32 tile per wave; 8 waves of a
// block share those lines through L1). Even/odd depth-1 register pipeline
// for all per-tile operands; compiler manages every waitcnt.
__global__ __launch_bounds__(512, 4) void k_attn(const float* __restrict__ adj,
                                                 const bf16* __restrict__ xt,
                                                 const bf16* __restrict__ xc,
                                                 const bf16* __restrict__ xtT,
                                                 bf16* __restrict__ sl0,
                                                 bf16* __restrict__ sl1,
                                                 bf16* __restrict__ sl2,
                                                 float* __restrict__ out) {
    int bid = blockIdx.x;
    int chunk = bid >> 8;                   // 0..3
    int bn = bid & 255;
    int nt = bn & 63, b = bn >> 6;
    int n0 = nt * 32;
    int wave = threadIdx.x >> 6;            // == head
    int lane = threadIdx.x & 63;
    int c = lane & 15, q = lane >> 4;
    int p = 8 * (c >> 2) + (c & 3);         // S A-row permutation
    size_t bh = (size_t)(b * HH + wave);
    const bf16* xt_h = xt + bh * NN * ATN;
    const bf16* xc_h = xc + bh * NN * ATN;
    const bf16* xtT_h = xtT + bh * ATN * NN;
    const float* adj_b = adj + (size_t)b * NN * NN;
    const int m_beg = chunk * 512;          // 16 tiles of 32

    // per-lane adj row bases (verified mapping from the R5 swizzle algebra):
    // A00[j] = adj[n0+c][m0+8q+j], A01 = next 16B, A10/A11 at row n0+16+c.
    const float* aR0 = adj_b + (size_t)(n0 + c) * NN + m_beg + q * 8;
    const float* aR1 = adj_b + (size_t)(n0 + 16 + c) * NN + m_beg + q * 8;

    bf16x8 bXC0 = *(const bf16x8*)(xc_h + (n0 + c) * ATN + q * 8);
    bf16x8 bXC1 = *(const bf16x8*)(xc_h + (n0 + 16 + c) * ATN + q * 8);
    f32x4 accO[2][2] = {};                  // O^T [oq][nq]
    const f32x4 z = {0.f, 0.f, 0.f, 0.f};

    // depth-1 register prefetch, explicit even/odd buffers
    bf16x8 xA0e, xA1e, oA0e, oA1e, xA0o, xA1o, oA0o, oA1o;
    f32x4  A00e, A01e, A10e, A11e, A00o, A01o, A10o, A11o;
#define REGS_E(t) do { int m0 = m_beg + (t) * 32;                              \
        xA0e = *(const bf16x8*)(xt_h + (size_t)(m0 + p) * ATN + q * 8);        \
        xA1e = *(const bf16x8*)(xt_h + (size_t)(m0 + p + 4) * ATN + q * 8);    \
        oA0e = *(const bf16x8*)(xtT_h + (size_t)(c) * NN + m0 + q * 8);        \
        oA1e = *(const bf16x8*)(xtT_h + (size_t)(16 + c) * NN + m0 + q * 8);   \
        A00e = *(const f32x4*)(aR0 + (t) * 32);                                \
        A01e = *(const f32x4*)(aR0 + (t) * 32 + 4);                            \
        A10e = *(const f32x4*)(aR1 + (t) * 32);                                \
        A11e = *(const f32x4*)(aR1 + (t) * 32 + 4);                            \
    } while (0)
#define REGS_O(t) do { int m0 = m_beg + (t) * 32;                              \
        xA0o = *(const bf16x8*)(xt_h + (size_t)(m0 + p) * ATN + q * 8);        \
        xA1o = *(const bf16x8*)(xt_h + (size_t)(m0 + p + 4) * ATN + q * 8);    \
        oA0o = *(const bf16x8*)(xtT_h + (size_t)(c) * NN + m0 + q * 8);        \
        oA1o = *(const bf16x8*)(xtT_h + (size_t)(16 + c) * NN + m0 + q * 8);   \
        A00o = *(const f32x4*)(aR0 + (t) * 32);                                \
        A01o = *(const f32x4*)(aR0 + (t) * 32 + 4);                            \
        A10o = *(const f32x4*)(aR1 + (t) * 32);                                \
        A11o = *(const f32x4*)(aR1 + (t) * 32 + 4);                            \
    } while (0)

#define COMPUTE(xA0, xA1, oA0, oA1, A00, A01, A10, A11) do {                   \
        f32x4 S0a = MFMA(xA0, bXC0, z);     /* S[m0+8q+r  ][n0+c]    */        \
        f32x4 S0b = MFMA(xA1, bXC0, z);     /* S[m0+8q+4+r][n0+c]    */        \
        f32x4 S1a = MFMA(xA0, bXC1, z);     /* S[m0+8q+r  ][n0+16+c] */        \
        f32x4 S1b = MFMA(xA1, bXC1, z);                                        \
        bf16x8 P0, P1;                                                         \
        _Pragma("unroll") for (int r = 0; r < 4; ++r) {                        \
            P0[r]     = (bf16)fast_tanh(S0a[r] * A00[r]);                      \
            P0[4 + r] = (bf16)fast_tanh(S0b[r] * A01[r]);                      \
            P1[r]     = (bf16)fast_tanh(S1a[r] * A10[r]);                      \
            P1[4 + r] = (bf16)fast_tanh(S1b[r] * A11[r]);                      \
        }                                                                      \
        accO[0][0] = MFMA(oA0, P0, accO[0][0]);                                \
        accO[0][1] = MFMA(oA0, P1, accO[0][1]);                                \
        accO[1][0] = MFMA(oA1, P0, accO[1][0]);                                \
        accO[1][1] = MFMA(oA1, P1, accO[1][1]);                                \
    } while (0)

    // ---- barrier-free pipeline: 16 tiles, depth-1 even/odd prefetch ----
    REGS_E(0);
#pragma unroll
    for (int tt = 0; tt < 14; tt += 2) {
        REGS_O(tt + 1);
        COMPUTE(xA0e, xA1e, oA0e, oA1e, A00e, A01e, A10e, A11e);
        REGS_E(tt + 2);
        COMPUTE(xA0o, xA1o, oA0o, oA1o, A00o, A01o, A10o, A11o);
    }
    REGS_O(15);
    COMPUTE(xA0e, xA1e, oA0e, oA1e, A00e, A01e, A10e, A11e);
    COMPUTE(xA0o, xA1o, oA0o, oA1o, A00o, A01o, A10o, A11o);

#undef REGS_E
#undef REGS_O
#undef COMPUTE

    // epilogue: O^T: o = wave*32 + oq*16 + 4q + r, n = n0 + nq*16 + c.
    // chunk 3 -> f32 out (plain store, covers every element once);
    // chunks 0-2 -> bf16 slabs; k_reduce sums.
    if (chunk == 3) {
#pragma unroll
        for (int oq = 0; oq < 2; ++oq)
#pragma unroll
            for (int nq = 0; nq < 2; ++nq) {
                size_t n = n0 + nq * 16 + c;
                *(f32x4*)&out[((size_t)b * NN + n) * 256 + wave * 32 + oq * 16 + 4 * q] =
                    accO[oq][nq];
            }
    } else {
        bf16* sl = (chunk == 0) ? sl0 : (chunk == 1 ? sl1 : sl2);
#pragma unroll
        for (int oq = 0; oq < 2; ++oq)
#pragma unroll
            for (int nq = 0; nq < 2; ++nq) {
                size_t n = n0 + nq * 16 + c;
                bf16x4 v;
#pragma unroll
                for (int r = 0; r < 4; ++r) v[r] = (bf16)accO[oq][nq][r];
                *(bf16x4*)&sl[((size_t)b * NN + n) * 256 + wave * 32 + oq * 16 + 4 * q] = v;
            }
    }
}

// ---------------- kernel C: out += sl0 + sl1 + sl2 ----------------
__global__ __launch_bounds__(256) void k_reduce(const bf16* __restrict__ sl0,
                                                const bf16* __restrict__ sl1,
                                                const bf16* __restrict__ sl2,
                                                float* __restrict__ out) {
    int i = blockIdx.x * 256 + threadIdx.x;   // f32x4 index, 524288 total
    f32x4 a = ((const f32x4*)out)[i];
    bf16x4 s0 = ((const bf16x4*)sl0)[i];
    bf16x4 s1 = ((const bf16x4*)sl1)[i];
    bf16x4 s2 = ((const bf16x4*)sl2)[i];
#pragma unroll
    for (int r = 0; r < 4; ++r)
        a[r] += (float)s0[r] + (float)s1[r] + (float)s2[r];
    ((f32x4*)out)[i] = a;
}

extern "C" void kernel_launch(void* const* d_in, const int* in_sizes, int n_in,
                              void* d_out, int out_size, void* d_ws, size_t ws_size,
                              hipStream_t stream) {
    const float* x    = (const float*)d_in[0];   // [4,2048,256]
    const float* adj  = (const float*)d_in[1];   // [4,2048,2048]
    const float* W    = (const float*)d_in[2];   // [8,256,32]
    const float* bias = (const float*)d_in[3];   // [8,32]
    const float* C    = (const float*)d_in[4];   // [8,32,32]
    float* out = (float*)d_out;                  // [4,2048,256]

    char* ws = (char*)d_ws;                      // 25.3 MB (same as proven R5)
    bf16*  xbf  = (bf16*)(ws + OFF_XBF);         // dead after k_proj -> slab0
    bf16*  xt   = (bf16*)(ws + OFF_XT);
    bf16*  xc   = (bf16*)(ws + OFF_XC);
    bf16*  xtT  = (bf16*)(ws + OFF_XTT);
    bf16*  WT   = (bf16*)(ws + OFF_WT);
    bf16*  Cb   = (bf16*)(ws + OFF_CB);
    bf16*  sl0  = (bf16*)(ws + OFF_XBF);         // reuse
    bf16*  sl1  = (bf16*)(ws + OFF_SLAB);
    bf16*  sl2  = (bf16*)(ws + OFF_SLAB + 4194304u);

    k_prep<<<2336, 256, 0, stream>>>(x, W, C, xbf, WT, Cb);
    k_proj<<<512, 256, 0, stream>>>(xbf, WT, Cb, bias, xt, xc, xtT);
    k_attn<<<1024, 512, 0, stream>>>(adj, xt, xc, xtT, sl0, sl1, sl2, out);
    k_reduce<<<2048, 256, 0, stream>>>(sl0, sl1, sl2, out);
}

// Round 2
// 168.723 us; speedup vs baseline: 1.4345x; 1.4345x over previous
//
#include <hip/hip_runtime.h>
#include <hip/hip_bf16.h>

// Problem: B=4, N=2048, IN=256, H=8, ATN=32
//   xt = x@W + b; xC = xt@C^T; S = xC@xt^T; alpha = tanh(S*adj);
//   out = concat_h(alpha @ xt)  [B,N,256] fp32
//
// R10: R9 post-mortem — removing barriers let the compiler collapse the
// software pipeline (VGPR 40: prefetch regs never allocated, loads sank to
// uses, ~900cy cold-HBM stall per tile per wave). The barrier/fence skeleton
// IS what pins the pipeline. So: revert to the R8-proven LDS-DMA structure
// and attack the real R8 limiter (60% idle = barrier drains; VALU the
// busiest real pipe) with two in-skeleton changes:
//   1) 2 tiles per barrier, 6 LDS buffers (24 KB): barriers 16 -> 8 per
//      chunk. DMA issued AFTER the barrier (all waves provably past the
//      buffer's last reader; overwrite distance 6 tiles, window exactly 6).
//      vmcnt: each fenced iteration issues exactly 2 DMA + 8 reg loads = 10
//      vmem -> steady wait vmcnt(10); tail (no DMA) -> vmcnt(8).
//   2) exp2-based exact tanh: 1 - 2/(exp2(2*log2e*x)+1) = 3 VALU + 2 trans
//      vs Pade's 8 VALU + 1 trans; no clamp needed (saturates at +-1).
//      Per-element issue 11 -> 7.

typedef __bf16 bf16;
typedef __attribute__((ext_vector_type(8))) __bf16 bf16x8;
typedef __attribute__((ext_vector_type(4))) __bf16 bf16x4;
typedef __attribute__((ext_vector_type(4))) float  f32x4;

#define MFMA(a, b, c) __builtin_amdgcn_mfma_f32_16x16x32_bf16(a, b, c, 0, 0, 0)

// async global->LDS DMA, 16 B/lane; LDS dest = wave-uniform base + lane*16
#define GLDS16(g, l) __builtin_amdgcn_global_load_lds(                        \
        (const __attribute__((address_space(1))) void*)(g),                   \
        (__attribute__((address_space(3))) void*)(l), 16, 0, 0)

// s_waitcnt imm: vmcnt[3:0] | expcnt(7)<<4 | lgkmcnt(15)<<8 | vmcnt[5:4]<<14
#define WAITVM10() __builtin_amdgcn_s_waitcnt(0x0F7A)
#define WAITVM8()  __builtin_amdgcn_s_waitcnt(0x0F78)
#define FENCE()    __builtin_amdgcn_sched_barrier(0)   // R5-proven: nothing crosses
#define BAR()      __builtin_amdgcn_s_barrier()

// Exact tanh via exp2 (3 VALU + 2 trans): 1 - 2/(e^{2x}+1).
// Saturates correctly for |x| large (exp2 -> inf/0), no clamp needed.
__device__ __forceinline__ float fast_tanh(float x) {
    float e = __builtin_amdgcn_exp2f(x * 2.88539008177792681f);  // 2*log2(e)
    float r = __builtin_amdgcn_rcpf(e + 1.0f);
    return __builtin_fmaf(-2.0f, r, 1.0f);
}

#define BB   4
#define NN   2048
#define IND  256
#define HH   8
#define ATN  32

// workspace layout (bytes) — total 25.3 MB (same proven footprint as R5)
#define OFF_XBF   0u           // x bf16 (4 MB); DEAD after k_proj -> reused as slab0
#define OFF_XT    4194304u
#define OFF_XC    8388608u
#define OFF_XTT   12582912u
#define OFF_WT    16777216u
#define OFF_CB    16908288u
#define OFF_SLAB  16924672u    // slab1 (4 MB bf16) + slab2 (4 MB bf16)

// ---------------- kernel 0: dtype conversion ----------------
__global__ __launch_bounds__(256) void k_prep(const float* __restrict__ x,
                                              const float* __restrict__ W,
                                              const float* __restrict__ C,
                                              bf16* __restrict__ xbf,
                                              bf16* __restrict__ WT,
                                              bf16* __restrict__ Cb) {
    int tid = blockIdx.x * 256 + threadIdx.x;
    if (tid < 524288) {
        float4 v = ((const float4*)x)[tid];
        bf16x4 o;
        o[0] = (bf16)v.x; o[1] = (bf16)v.y; o[2] = (bf16)v.z; o[3] = (bf16)v.w;
        *(bf16x4*)(xbf + (size_t)tid * 4) = o;
    } else if (tid < 524288 + 65536) {
        int t = tid - 524288;
        int h = t >> 13, r = t & 8191, i = r >> 5, o = r & 31;
        WT[(h * 32 + o) * 256 + i] = (bf16)W[t];
    } else if (tid < 524288 + 65536 + 8192) {
        int t = tid - (524288 + 65536);
        Cb[t] = (bf16)C[t];
    }
}

// ---------------- kernel A: projection ----------------
__global__ __launch_bounds__(256) void k_proj(const bf16* __restrict__ xbf,
                                              const bf16* __restrict__ WT,
                                              const bf16* __restrict__ Cb,
                                              const float* __restrict__ bias,
                                              bf16* __restrict__ xt,
                                              bf16* __restrict__ xc,
                                              bf16* __restrict__ xtT) {
    __shared__ bf16 ldsA_all[4][32 * 40];
    __shared__ bf16 ldsB_all[4][32 * 40];
    int bid = blockIdx.x;
    int ntg = bid & 15, h = (bid >> 4) & 7, b = bid >> 7;
    int wave = threadIdx.x >> 6;
    int lane = threadIdx.x & 63;
    int nt = ntg * 4 + wave;
    int n0 = nt * 32;
    int c = lane & 15, q = lane >> 4;
    bf16* ldsA = ldsA_all[wave];
    bf16* ldsB = ldsB_all[wave];

    f32x4 acc[2][2] = {};
    const bf16* xrow0 = xbf + ((size_t)(b * NN + n0 + c) * IND + q * 8);
    const bf16* xrow1 = xbf + ((size_t)(b * NN + n0 + 16 + c) * IND + q * 8);
    const bf16* wrow0 = WT + ((h * 32 + c) * IND + q * 8);
    const bf16* wrow1 = WT + ((h * 32 + 16 + c) * IND + q * 8);
#pragma unroll
    for (int k0 = 0; k0 < IND; k0 += 32) {
        bf16x8 a0 = *(const bf16x8*)(xrow0 + k0);
        bf16x8 a1 = *(const bf16x8*)(xrow1 + k0);
        bf16x8 w0 = *(const bf16x8*)(wrow0 + k0);
        bf16x8 w1 = *(const bf16x8*)(wrow1 + k0);
        acc[0][0] = MFMA(a0, w0, acc[0][0]);
        acc[0][1] = MFMA(a0, w1, acc[0][1]);
        acc[1][0] = MFMA(a1, w0, acc[1][0]);
        acc[1][1] = MFMA(a1, w1, acc[1][1]);
    }
    float bv[2] = { bias[h * 32 + c], bias[h * 32 + 16 + c] };
    size_t bh = (size_t)(b * HH + h);
#pragma unroll
    for (int nq = 0; nq < 2; ++nq)
#pragma unroll
        for (int oq = 0; oq < 2; ++oq)
#pragma unroll
            for (int r = 0; r < 4; ++r)
                ldsA[(nq * 16 + q * 4 + r) * 40 + oq * 16 + c] =
                    (bf16)(acc[nq][oq][r] + bv[oq]);
    f32x4 acc2[2][2] = {};
    bf16x8 aL0 = *(const bf16x8*)(ldsA + (c) * 40 + q * 8);
    bf16x8 aL1 = *(const bf16x8*)(ldsA + (16 + c) * 40 + q * 8);
    bf16x8 c0 = *(const bf16x8*)(Cb + h * 1024 + (c) * 32 + q * 8);
    bf16x8 c1 = *(const bf16x8*)(Cb + h * 1024 + (16 + c) * 32 + q * 8);
    acc2[0][0] = MFMA(aL0, c0, acc2[0][0]);
    acc2[0][1] = MFMA(aL0, c1, acc2[0][1]);
    acc2[1][0] = MFMA(aL1, c0, acc2[1][0]);
    acc2[1][1] = MFMA(aL1, c1, acc2[1][1]);
#pragma unroll
    for (int nq = 0; nq < 2; ++nq)
#pragma unroll
        for (int pq = 0; pq < 2; ++pq)
#pragma unroll
            for (int r = 0; r < 4; ++r)
                ldsB[(nq * 16 + q * 4 + r) * 40 + pq * 16 + c] =
                    (bf16)acc2[nq][pq][r];

    {   // coalesced xt/xc stores
        int n = lane >> 1, half = lane & 1;
        bf16x8 t0 = *(const bf16x8*)(ldsA + n * 40 + half * 16);
        bf16x8 t1 = *(const bf16x8*)(ldsA + n * 40 + half * 16 + 8);
        bf16* dst = xt + (bh * NN + n0 + n) * ATN + half * 16;
        *(bf16x8*)(dst) = t0;
        *(bf16x8*)(dst + 8) = t1;
        bf16x8 u0 = *(const bf16x8*)(ldsB + n * 40 + half * 16);
        bf16x8 u1 = *(const bf16x8*)(ldsB + n * 40 + half * 16 + 8);
        bf16* dst2 = xc + (bh * NN + n0 + n) * ATN + half * 16;
        *(bf16x8*)(dst2) = u0;
        *(bf16x8*)(dst2 + 8) = u1;
    }
    {   // xtT via LDS-gathered transpose
        int o = lane >> 1, nh = lane & 1;
        bf16x8 t0, t1;
#pragma unroll
        for (int i = 0; i < 8; ++i) {
            t0[i] = ldsA[(nh * 16 + i) * 40 + o];
            t1[i] = ldsA[(nh * 16 + 8 + i) * 40 + o];
        }
        bf16* dst = xtT + (bh * ATN + o) * NN + n0 + nh * 16;
        *(bf16x8*)(dst) = t0;
        *(bf16x8*)(dst + 8) = t1;
    }
}

// ---------------- kernel B: fused scores/tanh/PV, DMA-pipelined ----------------
// grid 1024 = chunk(4) * b(4) * ntile(64); 512 thr = 8 waves; wave == head.
// R8-proven skeleton (global_load_lds + XOR-swizzled source + raw s_barrier
// + manual vmcnt + mask-0 fences), restructured to 2 tiles per barrier with
// a 6-buffer LDS ring (24 KB):
//   prologue: DMA(0..3); REGS(0,1)
//   iter tt (tt=0,2,..,12): [FENCE WAITVM10 BAR FENCE]
//                           DMA(tt+4,tt+5)  <- after BAR: all waves are past
//                              COMPUTE(tt-2,tt-1), the last readers of the
//                              buffers being overwritten ((t+4)%6=(t-2)%6)
//                           COMPUTE(tt); COMPUTE(tt+1)
//                           [FENCE] REGS(tt+2,tt+3)
//   tail: [FENCE WAITVM8 BAR FENCE] COMPUTE(14); COMPUTE(15)
// vmcnt invariant: exactly 2 DMA + 8 reg-loads issue per iteration -> at
// each wait the 10 youngest vmem ops are DMA(tt+2,tt+3)+regs(8); waiting
// vmcnt(10) retires everything through DMA(tt+1). Last body issues no DMA
// -> tail waits vmcnt(8). Counts are set-robust to intra-region reordering
// because sched_barrier(0) bounds each region.
__global__ __launch_bounds__(512, 4) void k_attn(const float* __restrict__ adj,
                                                 const bf16* __restrict__ xt,
                                                 const bf16* __restrict__ xc,
                                                 const bf16* __restrict__ xtT,
                                                 bf16* __restrict__ sl0,
                                                 bf16* __restrict__ sl1,
                                                 bf16* __restrict__ sl2,
                                                 float* __restrict__ out) {
    __shared__ float adjlds[6 * 1024];      // 6 buffers x 32n x 32m fp32 (24 KB)
    int bid = blockIdx.x;
    int chunk = bid >> 8;                   // 0..3
    int bn = bid & 255;
    int nt = bn & 63, b = bn >> 6;
    int n0 = nt * 32;
    int wave = threadIdx.x >> 6;            // == head
    int lane = threadIdx.x & 63;
    int c = lane & 15, q = lane >> 4;
    int p = 8 * (c >> 2) + (c & 3);         // S A-row permutation
    size_t bh = (size_t)(b * HH + wave);
    const bf16* xt_h = xt + bh * NN * ATN;
    const bf16* xc_h = xc + bh * NN * ATN;
    const bf16* xtT_h = xtT + bh * ATN * NN;
    const float* adj_b = adj + (size_t)b * NN * NN;
    const int m_beg = chunk * 512;          // 16 tiles of 32

    // DMA source (waves 0-3): lane L covers 16B-block Bk = wave*64+L;
    // n = Bk>>3, sub' = Bk&7, global sub = sub' ^ (n&7)  (XOR swizzle)
    int nloc = wave * 8 + (lane >> 3);
    int gsub = (lane & 7) ^ (lane >> 3);
    const float* gA = adj_b + (size_t)(n0 + nloc) * NN + gsub * 4 + m_beg;

#define DMA(t) do { if (wave < 4)                                              \
        GLDS16(gA + (t) * 32, adjlds + ((t) % 6) * 1024 + wave * 256);         \
    } while (0)

    bf16x8 bXC0 = *(const bf16x8*)(xc_h + (n0 + c) * ATN + q * 8);
    bf16x8 bXC1 = *(const bf16x8*)(xc_h + (n0 + 16 + c) * ATN + q * 8);
    f32x4 accO[2][2] = {};                  // O^T [oq][nq]
    const f32x4 z = {0.f, 0.f, 0.f, 0.f};

    // depth-1 register prefetch, explicit even/odd buffers (R5-proven)
    bf16x8 xA0e, xA1e, oA0e, oA1e, xA0o, xA1o, oA0o, oA1o;
#define REGS_E(t) do { int m0 = m_beg + (t) * 32;                              \
        xA0e = *(const bf16x8*)(xt_h + (size_t)(m0 + p) * ATN + q * 8);        \
        xA1e = *(const bf16x8*)(xt_h + (size_t)(m0 + p + 4) * ATN + q * 8);    \
        oA0e = *(const bf16x8*)(xtT_h + (size_t)(c) * NN + m0 + q * 8);        \
        oA1e = *(const bf16x8*)(xtT_h + (size_t)(16 + c) * NN + m0 + q * 8);   \
    } while (0)
#define REGS_O(t) do { int m0 = m_beg + (t) * 32;                              \
        xA0o = *(const bf16x8*)(xt_h + (size_t)(m0 + p) * ATN + q * 8);        \
        xA1o = *(const bf16x8*)(xt_h + (size_t)(m0 + p + 4) * ATN + q * 8);    \
        oA0o = *(const bf16x8*)(xtT_h + (size_t)(c) * NN + m0 + q * 8);        \
        oA1o = *(const bf16x8*)(xtT_h + (size_t)(16 + c) * NN + m0 + q * 8);   \
    } while (0)

    // lane reads adj[n0+c(+16)][m0+8q..8q+7] from swizzled LDS tile
    int ad00 = c * 32 + ((2 * q) ^ (c & 7)) * 4;
    int ad01 = c * 32 + ((2 * q + 1) ^ (c & 7)) * 4;
    int ad10 = (16 + c) * 32 + ((2 * q) ^ (c & 7)) * 4;
    int ad11 = (16 + c) * 32 + ((2 * q + 1) ^ (c & 7)) * 4;

#define COMPUTE(t, xA0, xA1, oA0, oA1) do {                                    \
        const float* lb = adjlds + ((t) % 6) * 1024;                           \
        f32x4 A00 = *(const f32x4*)(lb + ad00);                                \
        f32x4 A01 = *(const f32x4*)(lb + ad01);                                \
        f32x4 A10 = *(const f32x4*)(lb + ad10);                                \
        f32x4 A11 = *(const f32x4*)(lb + ad11);                                \
        f32x4 S0a = MFMA(xA0, bXC0, z);     /* S[m0+8q+r  ][n0+c]    */        \
        f32x4 S0b = MFMA(xA1, bXC0, z);     /* S[m0+8q+4+r][n0+c]    */        \
        f32x4 S1a = MFMA(xA0, bXC1, z);     /* S[m0+8q+r  ][n0+16+c] */        \
        f32x4 S1b = MFMA(xA1, bXC1, z);                                        \
        bf16x8 P0, P1;                                                         \
        _Pragma("unroll") for (int r = 0; r < 4; ++r) {                        \
            P0[r]     = (bf16)fast_tanh(S0a[r] * A00[r]);                      \
            P0[4 + r] = (bf16)fast_tanh(S0b[r] * A01[r]);                      \
            P1[r]     = (bf16)fast_tanh(S1a[r] * A10[r]);                      \
            P1[4 + r] = (bf16)fast_tanh(S1b[r] * A11[r]);                      \
        }                                                                      \
        accO[0][0] = MFMA(oA0, P0, accO[0][0]);                                \
        accO[0][1] = MFMA(oA0, P1, accO[0][1]);                                \
        accO[1][0] = MFMA(oA1, P0, accO[1][0]);                                \
        accO[1][1] = MFMA(oA1, P1, accO[1][1]);                                \
    } while (0)

    // ---- pipeline: 6-buffer ring, 2 tiles per barrier (8 barriers) ----
    DMA(0); DMA(1); DMA(2); DMA(3);
    REGS_E(0); REGS_O(1);
#pragma unroll
    for (int tt = 0; tt <= 12; tt += 2) {
        FENCE(); WAITVM10(); BAR(); FENCE();
        if (tt + 4 < 16) { DMA(tt + 4); DMA(tt + 5); }
        COMPUTE(tt,     xA0e, xA1e, oA0e, oA1e);
        COMPUTE(tt + 1, xA0o, xA1o, oA0o, oA1o);
        FENCE();
        REGS_E(tt + 2); REGS_O(tt + 3);
    }
    // tail: tiles 14,15 (regs loaded in tt=12 body; DMA'd in tt=10 body)
    FENCE(); WAITVM8(); BAR(); FENCE();
    COMPUTE(14, xA0e, xA1e, oA0e, oA1e);
    COMPUTE(15, xA0o, xA1o, oA0o, oA1o);

#undef DMA
#undef REGS_E
#undef REGS_O
#undef COMPUTE

    // epilogue: O^T: o = wave*32 + oq*16 + 4q + r, n = n0 + nq*16 + c.
    // chunk 3 -> f32 out (plain store, covers every element once);
    // chunks 0-2 -> bf16 slabs; k_reduce sums.
    if (chunk == 3) {
#pragma unroll
        for (int oq = 0; oq < 2; ++oq)
#pragma unroll
            for (int nq = 0; nq < 2; ++nq) {
                size_t n = n0 + nq * 16 + c;
                *(f32x4*)&out[((size_t)b * NN + n) * 256 + wave * 32 + oq * 16 + 4 * q] =
                    accO[oq][nq];
            }
    } else {
        bf16* sl = (chunk == 0) ? sl0 : (chunk == 1 ? sl1 : sl2);
#pragma unroll
        for (int oq = 0; oq < 2; ++oq)
#pragma unroll
            for (int nq = 0; nq < 2; ++nq) {
                size_t n = n0 + nq * 16 + c;
                bf16x4 v;
#pragma unroll
                for (int r = 0; r < 4; ++r) v[r] = (bf16)accO[oq][nq][r];
                *(bf16x4*)&sl[((size_t)b * NN + n) * 256 + wave * 32 + oq * 16 + 4 * q] = v;
            }
    }
}

// ---------------- kernel C: out += sl0 + sl1 + sl2 ----------------
__global__ __launch_bounds__(256) void k_reduce(const bf16* __restrict__ sl0,
                                                const bf16* __restrict__ sl1,
                                                const bf16* __restrict__ sl2,
                                                float* __restrict__ out) {
    int i = blockIdx.x * 256 + threadIdx.x;   // f32x4 index, 524288 total
    f32x4 a = ((const f32x4*)out)[i];
    bf16x4 s0 = ((const bf16x4*)sl0)[i];
    bf16x4 s1 = ((const bf16x4*)sl1)[i];
    bf16x4 s2 = ((const bf16x4*)sl2)[i];
#pragma unroll
    for (int r = 0; r < 4; ++r)
        a[r] += (float)s0[r] + (float)s1[r] + (float)s2[r];
    ((f32x4*)out)[i] = a;
}

extern "C" void kernel_launch(void* const* d_in, const int* in_sizes, int n_in,
                              void* d_out, int out_size, void* d_ws, size_t ws_size,
                              hipStream_t stream) {
    const float* x    = (const float*)d_in[0];   // [4,2048,256]
    const float* adj  = (const float*)d_in[1];   // [4,2048,2048]
    const float* W    = (const float*)d_in[2];   // [8,256,32]
    const float* bias = (const float*)d_in[3];   // [8,32]
    const float* C    = (const float*)d_in[4];   // [8,32,32]
    float* out = (float*)d_out;                  // [4,2048,256]

    char* ws = (char*)d_ws;                      // 25.3 MB (same as proven R5)
    bf16*  xbf  = (bf16*)(ws + OFF_XBF);         // dead after k_proj -> slab0
    bf16*  xt   = (bf16*)(ws + OFF_XT);
    bf16*  xc   = (bf16*)(ws + OFF_XC);
    bf16*  xtT  = (bf16*)(ws + OFF_XTT);
    bf16*  WT   = (bf16*)(ws + OFF_WT);
    bf16*  Cb   = (bf16*)(ws + OFF_CB);
    bf16*  sl0  = (bf16*)(ws + OFF_XBF);         // reuse
    bf16*  sl1  = (bf16*)(ws + OFF_SLAB);
    bf16*  sl2  = (bf16*)(ws + OFF_SLAB + 4194304u);

    k_prep<<<2336, 256, 0, stream>>>(x, W, C, xbf, WT, Cb);
    k_proj<<<512, 256, 0, stream>>>(xbf, WT, Cb, bias, xt, xc, xtT);
    k_attn<<<1024, 512, 0, stream>>>(adj, xt, xc, xtT, sl0, sl1, sl2, out);
    k_reduce<<<2048, 256, 0, stream>>>(sl0, sl1, sl2, out);
}